// Round 1
// baseline (5637.189 us; speedup 1.0000x reference)
//
#include <hip/hip_runtime.h>

#define C_DIM 64
#define B_DIM 4

// One 64-lane wave per edge: lane = b*16 + c4  (b in [0,4), c4 in [0,16))
// Each lane gathers float4 of h[b, src, c4*4..] and atomically adds into agg[b, dst, ...].
__global__ __launch_bounds__(256) void gin_scatter(
    const float* __restrict__ h, const int* __restrict__ src,
    const int* __restrict__ dst, float* __restrict__ agg,
    int n_edges, int n_nodes)
{
    long long i = (long long)blockIdx.x * blockDim.x + threadIdx.x;
    int e = (int)(i >> 6);
    if (e >= n_edges) return;
    int lane = (int)(i & 63);
    int b  = lane >> 4;
    int c4 = (lane & 15) << 2;
    int s = src[e];
    int d = dst[e];
    const float4 v = *reinterpret_cast<const float4*>(
        h + ((size_t)b * n_nodes + s) * C_DIM + c4);
    float* o = agg + ((size_t)b * n_nodes + d) * C_DIM + c4;
    unsafeAtomicAdd(o + 0, v.x);
    unsafeAtomicAdd(o + 1, v.y);
    unsafeAtomicAdd(o + 2, v.z);
    unsafeAtomicAdd(o + 3, v.w);
}

// out[row, j] = bias[j] + sum_k (hin[row,k] + agg[row,k]) * W[j,k]
// 256 threads = 4 rows per block, one thread per (row, out-channel).
// W staged in LDS padded to 65 (stride 65 % 32 = 1 -> conflict-free column reads).
// Safe for hin == out: rows are read into LDS before any write, and each block
// only writes its own rows.
__global__ __launch_bounds__(256) void gin_mm(
    const float* __restrict__ hin, const float* __restrict__ agg,
    const float* __restrict__ W, const float* __restrict__ bias,
    float* __restrict__ out, int M)
{
    __shared__ float Ws[64][65];
    __shared__ float rows[4][64];
    int tid = threadIdx.x;
    for (int i = tid; i < 64 * 64; i += 256)
        Ws[i >> 6][i & 63] = W[i];
    int rloc = tid >> 6;
    int j    = tid & 63;
    int row  = blockIdx.x * 4 + rloc;
    if (row < M)
        rows[rloc][j] = hin[(size_t)row * C_DIM + j] + agg[(size_t)row * C_DIM + j];
    __syncthreads();
    if (row < M) {
        float acc = bias[j];
#pragma unroll
        for (int k = 0; k < 64; ++k)
            acc += rows[rloc][k] * Ws[j][k];
        out[(size_t)row * C_DIM + j] = acc;
    }
}

extern "C" void kernel_launch(void* const* d_in, const int* in_sizes, int n_in,
                              void* d_out, int out_size, void* d_ws, size_t ws_size,
                              hipStream_t stream)
{
    const float* x   = (const float*)d_in[0];
    const int*   ei  = (const int*)d_in[1];   // (2, E): row 0 = src, row 1 = dst
    const float* W1  = (const float*)d_in[2];
    const float* b1  = (const float*)d_in[3];
    const float* W2  = (const float*)d_in[4];
    const float* b2  = (const float*)d_in[5];
    float* out = (float*)d_out;

    const int n_nodes = in_sizes[0] / (B_DIM * C_DIM);
    const int n_edges = in_sizes[1] / 2;
    const int M = B_DIM * n_nodes;               // total rows
    const size_t agg_bytes = (size_t)M * C_DIM * sizeof(float);

    const int* src = ei;
    const int* dst = ei + n_edges;

    float* agg = (float*)d_ws;

    dim3 blk(256);
    dim3 grid_sc((unsigned)(((long long)n_edges * 64 + 255) / 256));
    dim3 grid_mm((unsigned)((M + 3) / 4));

    // ---- Layer 1 ----
    hipMemsetAsync(agg, 0, agg_bytes, stream);
    gin_scatter<<<grid_sc, blk, 0, stream>>>(x, src, dst, agg, n_edges, n_nodes);
    gin_mm<<<grid_mm, blk, 0, stream>>>(x, agg, W1, b1, out, M);

    // ---- Layer 2 (in-place on out) ----
    hipMemsetAsync(agg, 0, agg_bytes, stream);
    gin_scatter<<<grid_sc, blk, 0, stream>>>(out, src, dst, agg, n_edges, n_nodes);
    gin_mm<<<grid_mm, blk, 0, stream>>>(out, agg, W2, b2, out, M);
}

// Round 2
// 477.687 us; speedup vs baseline: 11.8010x; 11.8010x over previous
//
#include <hip/hip_runtime.h>

#define C_DIM 64
#define B_DIM 4

// ---------------- CSR build ----------------

__global__ __launch_bounds__(256) void k_hist(
    const int* __restrict__ dst, int* __restrict__ counts, int n_edges)
{
    int e = blockIdx.x * 256 + threadIdx.x;
    if (e < n_edges) atomicAdd(&counts[dst[e]], 1);
}

// partial sums: block b -> partials[b] = sum of its 256-count chunk
__global__ __launch_bounds__(256) void k_part(
    const int* __restrict__ counts, int* __restrict__ partials, int n_nodes)
{
    __shared__ int s[256];
    int i = blockIdx.x * 256 + threadIdx.x;
    int v = (i < n_nodes) ? counts[i] : 0;
    s[threadIdx.x] = v;
    __syncthreads();
    for (int d = 128; d > 0; d >>= 1) {
        if (threadIdx.x < d) s[threadIdx.x] += s[threadIdx.x + d];
        __syncthreads();
    }
    if (threadIdx.x == 0) partials[blockIdx.x] = s[0];
}

// exclusive scan of partials (nb <= 256) in one block
__global__ __launch_bounds__(256) void k_scan1(
    int* __restrict__ partials, int nb)
{
    __shared__ int s[256];
    int tid = threadIdx.x;
    int v = (tid < nb) ? partials[tid] : 0;
    s[tid] = v;
    __syncthreads();
    for (int d = 1; d < 256; d <<= 1) {
        int t = (tid >= d) ? s[tid - d] : 0;
        __syncthreads();
        s[tid] += t;
        __syncthreads();
    }
    if (tid < nb) partials[tid] = s[tid] - v;   // exclusive
}

// offsets[i] = partials[blk] + exclusive_scan_within_block(counts); cursor = offsets
__global__ __launch_bounds__(256) void k_final(
    const int* __restrict__ counts, const int* __restrict__ partials,
    int* __restrict__ offsets, int* __restrict__ cursor, int n_nodes)
{
    __shared__ int s[256];
    int tid = threadIdx.x;
    int i = blockIdx.x * 256 + tid;
    int v = (i < n_nodes) ? counts[i] : 0;
    s[tid] = v;
    __syncthreads();
    for (int d = 1; d < 256; d <<= 1) {
        int t = (tid >= d) ? s[tid - d] : 0;
        __syncthreads();
        s[tid] += t;
        __syncthreads();
    }
    if (i < n_nodes) {
        int off = partials[blockIdx.x] + s[tid] - v;
        offsets[i] = off;
        cursor[i] = off;
    }
}

__global__ __launch_bounds__(256) void k_fill(
    const int* __restrict__ src, const int* __restrict__ dst,
    int* __restrict__ cursor, unsigned short* __restrict__ elist, int n_edges)
{
    int e = blockIdx.x * 256 + threadIdx.x;
    if (e < n_edges) {
        int pos = atomicAdd(&cursor[dst[e]], 1);
        elist[pos] = (unsigned short)src[e];
    }
}

// ---------------- fused gather + self + 64x64 matmul ----------------
// one block per node; thread (b = tid>>6, c = tid&63)
__global__ __launch_bounds__(256) void gin_fused(
    const float* __restrict__ hin, const unsigned short* __restrict__ elist,
    const int* __restrict__ offsets, const float* __restrict__ W,
    const float* __restrict__ bias, float* __restrict__ hout,
    int n_nodes, int n_edges)
{
    __shared__ float Ws[64][65];
    __shared__ float rows[4][64];
    int tid = threadIdx.x;
    for (int i = tid; i < 64 * 64; i += 256)
        Ws[i >> 6][i & 63] = W[i];

    int b = tid >> 6;
    int c = tid & 63;
    int node = blockIdx.x;
    int row_start = offsets[node];
    int row_end = (node + 1 < n_nodes) ? offsets[node + 1] : n_edges;

    int base = b * n_nodes;                         // fits in int (4*50000)
    float acc = hin[(size_t)((base + node) << 6) + c];  // self term

    int k = row_start;
    for (; k + 4 <= row_end; k += 4) {
        int s0 = elist[k + 0];
        int s1 = elist[k + 1];
        int s2 = elist[k + 2];
        int s3 = elist[k + 3];
        float v0 = hin[(size_t)((base + s0) << 6) + c];
        float v1 = hin[(size_t)((base + s1) << 6) + c];
        float v2 = hin[(size_t)((base + s2) << 6) + c];
        float v3 = hin[(size_t)((base + s3) << 6) + c];
        acc += v0; acc += v1; acc += v2; acc += v3;
    }
    for (; k < row_end; ++k) {
        int s = elist[k];
        acc += hin[(size_t)((base + s) << 6) + c];
    }

    rows[b][c] = acc;
    __syncthreads();

    float o = bias[c];
#pragma unroll
    for (int kk = 0; kk < 64; ++kk)
        o += rows[b][kk] * Ws[c][kk];
    hout[(size_t)((base + node) << 6) + c] = o;
}

// ---------------- fallback (round-1 atomic path) ----------------

__global__ __launch_bounds__(256) void gin_scatter(
    const float* __restrict__ h, const int* __restrict__ src,
    const int* __restrict__ dst, float* __restrict__ agg,
    int n_edges, int n_nodes)
{
    long long i = (long long)blockIdx.x * blockDim.x + threadIdx.x;
    int e = (int)(i >> 6);
    if (e >= n_edges) return;
    int lane = (int)(i & 63);
    int b  = lane >> 4;
    int c4 = (lane & 15) << 2;
    int s = src[e];
    int d = dst[e];
    const float4 v = *reinterpret_cast<const float4*>(
        h + ((size_t)b * n_nodes + s) * C_DIM + c4);
    float* o = agg + ((size_t)b * n_nodes + d) * C_DIM + c4;
    unsafeAtomicAdd(o + 0, v.x);
    unsafeAtomicAdd(o + 1, v.y);
    unsafeAtomicAdd(o + 2, v.z);
    unsafeAtomicAdd(o + 3, v.w);
}

__global__ __launch_bounds__(256) void gin_mm(
    const float* __restrict__ hin, const float* __restrict__ agg,
    const float* __restrict__ W, const float* __restrict__ bias,
    float* __restrict__ out, int M)
{
    __shared__ float Ws[64][65];
    __shared__ float rows[4][64];
    int tid = threadIdx.x;
    for (int i = tid; i < 64 * 64; i += 256)
        Ws[i >> 6][i & 63] = W[i];
    int rloc = tid >> 6;
    int j    = tid & 63;
    int row  = blockIdx.x * 4 + rloc;
    if (row < M)
        rows[rloc][j] = hin[(size_t)row * C_DIM + j] + agg[(size_t)row * C_DIM + j];
    __syncthreads();
    if (row < M) {
        float acc = bias[j];
#pragma unroll
        for (int k = 0; k < 64; ++k)
            acc += rows[rloc][k] * Ws[j][k];
        out[(size_t)row * C_DIM + j] = acc;
    }
}

// ---------------- launch ----------------

static inline size_t align256(size_t x) { return (x + 255) & ~(size_t)255; }

extern "C" void kernel_launch(void* const* d_in, const int* in_sizes, int n_in,
                              void* d_out, int out_size, void* d_ws, size_t ws_size,
                              hipStream_t stream)
{
    const float* x   = (const float*)d_in[0];
    const int*   ei  = (const int*)d_in[1];
    const float* W1  = (const float*)d_in[2];
    const float* b1  = (const float*)d_in[3];
    const float* W2  = (const float*)d_in[4];
    const float* b2  = (const float*)d_in[5];
    float* out = (float*)d_out;

    const int n_nodes = in_sizes[0] / (B_DIM * C_DIM);
    const int n_edges = in_sizes[1] / 2;
    const int M = B_DIM * n_nodes;
    const size_t h_bytes = (size_t)M * C_DIM * sizeof(float);

    const int* src = ei;
    const int* dst = ei + n_edges;

    const int NB = (n_nodes + 255) / 256;

    // ws layout (fast path)
    size_t off = 0;
    size_t o_h1      = off; off = align256(off + h_bytes);
    size_t o_counts  = off; off = align256(off + (size_t)n_nodes * sizeof(int));
    size_t o_offsets = off; off = align256(off + (size_t)n_nodes * sizeof(int));
    size_t o_cursor  = off; off = align256(off + (size_t)n_nodes * sizeof(int));
    size_t o_part    = off; off = align256(off + 256 * sizeof(int));
    size_t o_elist   = off; off = align256(off + (size_t)n_edges * sizeof(unsigned short));
    const size_t need = off;

    const bool fast = (ws_size >= need) && (n_nodes <= 65536) && (NB <= 256);

    dim3 blk(256);

    if (fast) {
        char* ws = (char*)d_ws;
        float* h1             = (float*)(ws + o_h1);
        int* counts           = (int*)(ws + o_counts);
        int* offsets          = (int*)(ws + o_offsets);
        int* cursor           = (int*)(ws + o_cursor);
        int* partials         = (int*)(ws + o_part);
        unsigned short* elist = (unsigned short*)(ws + o_elist);

        dim3 grid_e((n_edges + 255) / 256);
        dim3 grid_n((unsigned)NB);
        dim3 grid_node((unsigned)n_nodes);

        hipMemsetAsync(counts, 0, (size_t)n_nodes * sizeof(int), stream);
        k_hist<<<grid_e, blk, 0, stream>>>(dst, counts, n_edges);
        k_part<<<grid_n, blk, 0, stream>>>(counts, partials, n_nodes);
        k_scan1<<<1, blk, 0, stream>>>(partials, NB);
        k_final<<<grid_n, blk, 0, stream>>>(counts, partials, offsets, cursor, n_nodes);
        k_fill<<<grid_e, blk, 0, stream>>>(src, dst, cursor, elist, n_edges);

        gin_fused<<<grid_node, blk, 0, stream>>>(x,  elist, offsets, W1, b1, h1,  n_nodes, n_edges);
        gin_fused<<<grid_node, blk, 0, stream>>>(h1, elist, offsets, W2, b2, out, n_nodes, n_edges);
    } else {
        // fallback: proven atomic path (ws >= one h-sized buffer)
        float* agg = (float*)d_ws;
        dim3 grid_sc((unsigned)(((long long)n_edges * 64 + 255) / 256));
        dim3 grid_mm((unsigned)((M + 3) / 4));

        hipMemsetAsync(agg, 0, h_bytes, stream);
        gin_scatter<<<grid_sc, blk, 0, stream>>>(x, src, dst, agg, n_edges, n_nodes);
        gin_mm<<<grid_mm, blk, 0, stream>>>(x, agg, W1, b1, out, M);

        hipMemsetAsync(agg, 0, h_bytes, stream);
        gin_scatter<<<grid_sc, blk, 0, stream>>>(out, src, dst, agg, n_edges, n_nodes);
        gin_mm<<<grid_mm, blk, 0, stream>>>(out, agg, W2, b2, out, M);
    }
}

// Round 3
// 380.510 us; speedup vs baseline: 14.8148x; 1.2554x over previous
//
#include <hip/hip_runtime.h>

#define C_DIM 64
#define B_DIM 4

typedef unsigned short u16;
typedef unsigned int u32;

__device__ __forceinline__ float bf2f(u16 v) {
    union { u32 u; float f; } t; t.u = ((u32)v) << 16; return t.f;
}
__device__ __forceinline__ u16 f2bf(float f) {
    union { u32 u; float f; } t; t.f = f;
    u32 u = t.u;
    return (u16)((u + 0x7FFF + ((u >> 16) & 1)) >> 16);  // RNE
}

// ---------------- fp32 -> bf16 conversion (8 elems/thread) ----------------
__global__ __launch_bounds__(256) void k_f2bf(
    const float* __restrict__ in, u16* __restrict__ outb, int n8)
{
    int i = blockIdx.x * 256 + threadIdx.x;
    if (i >= n8) return;
    const float4* p = (const float4*)(in + (size_t)i * 8);
    float4 a = p[0], b = p[1];
    ushort4 lo, hi;
    lo.x = f2bf(a.x); lo.y = f2bf(a.y); lo.z = f2bf(a.z); lo.w = f2bf(a.w);
    hi.x = f2bf(b.x); hi.y = f2bf(b.y); hi.z = f2bf(b.z); hi.w = f2bf(b.w);
    ushort4* q = (ushort4*)(outb + (size_t)i * 8);
    q[0] = lo; q[1] = hi;
}

// ---------------- CSR build ----------------

__global__ __launch_bounds__(256) void k_hist(
    const int* __restrict__ dst, int* __restrict__ counts, int n_edges)
{
    int e = blockIdx.x * 256 + threadIdx.x;
    if (e < n_edges) atomicAdd(&counts[dst[e]], 1);
}

__global__ __launch_bounds__(256) void k_part(
    const int* __restrict__ counts, int* __restrict__ partials, int n_nodes)
{
    __shared__ int s[256];
    int i = blockIdx.x * 256 + threadIdx.x;
    int v = (i < n_nodes) ? counts[i] : 0;
    s[threadIdx.x] = v;
    __syncthreads();
    for (int d = 128; d > 0; d >>= 1) {
        if (threadIdx.x < d) s[threadIdx.x] += s[threadIdx.x + d];
        __syncthreads();
    }
    if (threadIdx.x == 0) partials[blockIdx.x] = s[0];
}

__global__ __launch_bounds__(256) void k_scan1(
    int* __restrict__ partials, int nb)
{
    __shared__ int s[256];
    int tid = threadIdx.x;
    int v = (tid < nb) ? partials[tid] : 0;
    s[tid] = v;
    __syncthreads();
    for (int d = 1; d < 256; d <<= 1) {
        int t = (tid >= d) ? s[tid - d] : 0;
        __syncthreads();
        s[tid] += t;
        __syncthreads();
    }
    if (tid < nb) partials[tid] = s[tid] - v;   // exclusive
}

__global__ __launch_bounds__(256) void k_final(
    const int* __restrict__ counts, const int* __restrict__ partials,
    int* __restrict__ offsets, int* __restrict__ cursor, int n_nodes)
{
    __shared__ int s[256];
    int tid = threadIdx.x;
    int i = blockIdx.x * 256 + tid;
    int v = (i < n_nodes) ? counts[i] : 0;
    s[tid] = v;
    __syncthreads();
    for (int d = 1; d < 256; d <<= 1) {
        int t = (tid >= d) ? s[tid - d] : 0;
        __syncthreads();
        s[tid] += t;
        __syncthreads();
    }
    if (i < n_nodes) {
        int off = partials[blockIdx.x] + s[tid] - v;
        offsets[i] = off;
        cursor[i] = off;
    }
}

__global__ __launch_bounds__(256) void k_fill(
    const int* __restrict__ src, const int* __restrict__ dst,
    int* __restrict__ cursor, u16* __restrict__ elist, int n_edges)
{
    int e = blockIdx.x * 256 + threadIdx.x;
    if (e < n_edges) {
        int pos = atomicAdd(&cursor[dst[e]], 1);
        elist[pos] = (u16)src[e];
    }
}

// ---------------- fused gather + self + 64x64 matmul (bf16 in) ----------------
// grid-stride; block = 4 nodes x 1 batch; batch pinned to an XCD pair via
// blockIdx%8 (bid8>>1 = batch). wave r handles node g*4+r, lane c = channel.
__global__ __launch_bounds__(256) void gin_fused2(
    const u16* __restrict__ hb,       // bf16 (B, N, 64)
    const u16* __restrict__ elist,
    const int* __restrict__ offsets,
    const float* __restrict__ W,      // (64, 64) row-major (out, in)
    const float* __restrict__ bias,
    float* __restrict__ out_f32,      // nullable
    u16* __restrict__ out_bf,         // nullable
    int n_nodes, int n_edges, int groups_per_batch)
{
    __shared__ float Ws[64][65];
    __shared__ float rows[2][4][64];
    int tid = threadIdx.x;
    for (int i = tid; i < 64 * 64; i += 256)
        Ws[i >> 6][i & 63] = W[i];
    __syncthreads();

    int r = tid >> 6;                 // node within group
    int c = tid & 63;                 // channel
    int bid8 = blockIdx.x & 7;
    int batch = bid8 >> 1;
    int blk_in_batch = ((blockIdx.x >> 3) << 1) | (bid8 & 1);
    int stride = gridDim.x >> 2;      // blocks per batch
    size_t bbase = (size_t)batch * n_nodes;
    size_t lane_off = (bbase << 6) + c;
    float bia = bias[c];

    int p = 0;
    for (int g = blk_in_batch; g < groups_per_batch; g += stride, p ^= 1) {
        int node = g * 4 + r;
        float acc = 0.f;
        if (node < n_nodes) {
            int row_start = offsets[node];
            int row_end = (node + 1 < n_nodes) ? offsets[node + 1] : n_edges;
            acc = bf2f(hb[lane_off + ((size_t)node << 6)]);   // self term
            int k = row_start;
            for (; k + 4 <= row_end; k += 4) {
                int s0 = elist[k + 0];
                int s1 = elist[k + 1];
                int s2 = elist[k + 2];
                int s3 = elist[k + 3];
                float v0 = bf2f(hb[lane_off + ((size_t)s0 << 6)]);
                float v1 = bf2f(hb[lane_off + ((size_t)s1 << 6)]);
                float v2 = bf2f(hb[lane_off + ((size_t)s2 << 6)]);
                float v3 = bf2f(hb[lane_off + ((size_t)s3 << 6)]);
                acc += v0; acc += v1; acc += v2; acc += v3;
            }
            for (; k < row_end; ++k)
                acc += bf2f(hb[lane_off + ((size_t)elist[k] << 6)]);
        }
        rows[p][r][c] = acc;
        __syncthreads();
        if (node < n_nodes) {
            float o = bia;
#pragma unroll
            for (int kk = 0; kk < 64; ++kk)
                o += rows[p][r][kk] * Ws[c][kk];
            size_t oi = ((bbase + node) << 6) + c;
            if (out_f32) out_f32[oi] = o;
            if (out_bf)  out_bf[oi]  = f2bf(o);
        }
    }
}

// ---------------- fallback (atomic path, proven) ----------------

__global__ __launch_bounds__(256) void gin_scatter(
    const float* __restrict__ h, const int* __restrict__ src,
    const int* __restrict__ dst, float* __restrict__ agg,
    int n_edges, int n_nodes)
{
    long long i = (long long)blockIdx.x * blockDim.x + threadIdx.x;
    int e = (int)(i >> 6);
    if (e >= n_edges) return;
    int lane = (int)(i & 63);
    int b  = lane >> 4;
    int c4 = (lane & 15) << 2;
    int s = src[e];
    int d = dst[e];
    const float4 v = *reinterpret_cast<const float4*>(
        h + ((size_t)b * n_nodes + s) * C_DIM + c4);
    float* o = agg + ((size_t)b * n_nodes + d) * C_DIM + c4;
    unsafeAtomicAdd(o + 0, v.x);
    unsafeAtomicAdd(o + 1, v.y);
    unsafeAtomicAdd(o + 2, v.z);
    unsafeAtomicAdd(o + 3, v.w);
}

__global__ __launch_bounds__(256) void gin_mm(
    const float* __restrict__ hin, const float* __restrict__ agg,
    const float* __restrict__ W, const float* __restrict__ bias,
    float* __restrict__ out, int M)
{
    __shared__ float Ws[64][65];
    __shared__ float rows[4][64];
    int tid = threadIdx.x;
    for (int i = tid; i < 64 * 64; i += 256)
        Ws[i >> 6][i & 63] = W[i];
    int rloc = tid >> 6;
    int j    = tid & 63;
    int row  = blockIdx.x * 4 + rloc;
    if (row < M)
        rows[rloc][j] = hin[(size_t)row * C_DIM + j] + agg[(size_t)row * C_DIM + j];
    __syncthreads();
    if (row < M) {
        float acc = bias[j];
#pragma unroll
        for (int k = 0; k < 64; ++k)
            acc += rows[rloc][k] * Ws[j][k];
        out[(size_t)row * C_DIM + j] = acc;
    }
}

// ---------------- launch ----------------

static inline size_t align256(size_t x) { return (x + 255) & ~(size_t)255; }

extern "C" void kernel_launch(void* const* d_in, const int* in_sizes, int n_in,
                              void* d_out, int out_size, void* d_ws, size_t ws_size,
                              hipStream_t stream)
{
    const float* x   = (const float*)d_in[0];
    const int*   ei  = (const int*)d_in[1];
    const float* W1  = (const float*)d_in[2];
    const float* b1  = (const float*)d_in[3];
    const float* W2  = (const float*)d_in[4];
    const float* b2  = (const float*)d_in[5];
    float* out = (float*)d_out;

    const int n_nodes = in_sizes[0] / (B_DIM * C_DIM);
    const int n_edges = in_sizes[1] / 2;
    const int M = B_DIM * n_nodes;
    const size_t elems = (size_t)M * C_DIM;

    const int* src = ei;
    const int* dst = ei + n_edges;
    const int NB = (n_nodes + 255) / 256;

    // ws layout (fast path)
    size_t off = 0;
    size_t o_xb      = off; off = align256(off + elems * sizeof(u16));
    size_t o_h1b     = off; off = align256(off + elems * sizeof(u16));
    size_t o_counts  = off; off = align256(off + (size_t)n_nodes * sizeof(int));
    size_t o_offsets = off; off = align256(off + (size_t)n_nodes * sizeof(int));
    size_t o_cursor  = off; off = align256(off + (size_t)n_nodes * sizeof(int));
    size_t o_part    = off; off = align256(off + 256 * sizeof(int));
    size_t o_elist   = off; off = align256(off + (size_t)n_edges * sizeof(u16));
    const size_t need = off;

    const bool fast = (ws_size >= need) && (n_nodes <= 65535) && (NB <= 256) &&
                      ((elems & 7) == 0);

    dim3 blk(256);

    if (fast) {
        char* ws = (char*)d_ws;
        u16* xb      = (u16*)(ws + o_xb);
        u16* h1b     = (u16*)(ws + o_h1b);
        int* counts  = (int*)(ws + o_counts);
        int* offsets = (int*)(ws + o_offsets);
        int* cursor  = (int*)(ws + o_cursor);
        int* partials= (int*)(ws + o_part);
        u16* elist   = (u16*)(ws + o_elist);

        int n8 = (int)(elems / 8);
        dim3 grid_cv((n8 + 255) / 256);
        dim3 grid_e((n_edges + 255) / 256);
        dim3 grid_n((unsigned)NB);

        const int GRID_F = 4096;               // multiple of 8
        const int groups = (n_nodes + 3) / 4;  // per batch
        dim3 grid_f(GRID_F);

        // CSR build + conversion
        hipMemsetAsync(counts, 0, (size_t)n_nodes * sizeof(int), stream);
        k_f2bf<<<grid_cv, blk, 0, stream>>>(x, xb, n8);
        k_hist<<<grid_e, blk, 0, stream>>>(dst, counts, n_edges);
        k_part<<<grid_n, blk, 0, stream>>>(counts, partials, n_nodes);
        k_scan1<<<1, blk, 0, stream>>>(partials, NB);
        k_final<<<grid_n, blk, 0, stream>>>(counts, partials, offsets, cursor, n_nodes);
        k_fill<<<grid_e, blk, 0, stream>>>(src, dst, cursor, elist, n_edges);

        // layer 1: bf16 in -> bf16 out (h1b only)
        gin_fused2<<<grid_f, blk, 0, stream>>>(xb, elist, offsets, W1, b1,
                                               nullptr, h1b, n_nodes, n_edges, groups);
        // layer 2: bf16 in -> fp32 out
        gin_fused2<<<grid_f, blk, 0, stream>>>(h1b, elist, offsets, W2, b2,
                                               out, nullptr, n_nodes, n_edges, groups);
    } else {
        // fallback: atomic path
        float* agg = (float*)d_ws;
        const size_t h_bytes = elems * sizeof(float);
        dim3 grid_sc((unsigned)(((long long)n_edges * 64 + 255) / 256));
        dim3 grid_mm((unsigned)((M + 3) / 4));

        hipMemsetAsync(agg, 0, h_bytes, stream);
        gin_scatter<<<grid_sc, blk, 0, stream>>>(x, src, dst, agg, n_edges, n_nodes);
        gin_mm<<<grid_mm, blk, 0, stream>>>(x, agg, W1, b1, out, M);

        hipMemsetAsync(agg, 0, h_bytes, stream);
        gin_scatter<<<grid_sc, blk, 0, stream>>>(out, src, dst, agg, n_edges, n_nodes);
        gin_mm<<<grid_mm, blk, 0, stream>>>(out, agg, W2, b2, out, M);
    }
}

// Round 4
// 294.677 us; speedup vs baseline: 19.1301x; 1.2913x over previous
//
#include <hip/hip_runtime.h>

#define C_DIM 64
#define B_DIM 4

typedef unsigned short u16;
typedef unsigned int u32;

__device__ __forceinline__ float bf2f(u16 v) {
    union { u32 u; float f; } t; t.u = ((u32)v) << 16; return t.f;
}
__device__ __forceinline__ u16 f2bf(float f) {
    union { u32 u; float f; } t; t.f = f;
    u32 u = t.u;
    return (u16)((u + 0x7FFF + ((u >> 16) & 1)) >> 16);  // RNE
}
__device__ __forceinline__ float lo16(u32 u) {
    union { u32 v; float f; } t; t.v = u << 16; return t.f;
}
__device__ __forceinline__ float hi16(u32 u) {
    union { u32 v; float f; } t; t.v = u & 0xffff0000u; return t.f;
}

// ---- fp32 (B,N,C) -> bf16 (N, B*C) transpose+convert, 8 elems/thread ----
__global__ __launch_bounds__(256) void k_f2bf_t(
    const float* __restrict__ in, u16* __restrict__ outb, int n_nodes)
{
    int i = blockIdx.x * 256 + threadIdx.x;      // [0, n_nodes*32)
    if (i >= n_nodes * 32) return;
    int n = i >> 5;
    int r = i & 31;
    int b = r >> 3, c8 = (r & 7) << 3;
    const float4* p = (const float4*)(in + ((size_t)b * n_nodes + n) * 64 + c8);
    float4 A = p[0], B = p[1];
    ushort4 lo, hi;
    lo.x = f2bf(A.x); lo.y = f2bf(A.y); lo.z = f2bf(A.z); lo.w = f2bf(A.w);
    hi.x = f2bf(B.x); hi.y = f2bf(B.y); hi.z = f2bf(B.z); hi.w = f2bf(B.w);
    ushort4* q = (ushort4*)(outb + (size_t)n * 256 + b * 64 + c8);
    q[0] = lo; q[1] = hi;
}

// ---------------- CSR build ----------------

__global__ __launch_bounds__(256) void k_hist(
    const int* __restrict__ dst, int* __restrict__ counts, int n_edges)
{
    int e = blockIdx.x * 256 + threadIdx.x;
    if (e < n_edges) atomicAdd(&counts[dst[e]], 1);
}

__global__ __launch_bounds__(256) void k_part(
    const int* __restrict__ counts, int* __restrict__ partials, int n_nodes)
{
    __shared__ int s[256];
    int i = blockIdx.x * 256 + threadIdx.x;
    int v = (i < n_nodes) ? counts[i] : 0;
    s[threadIdx.x] = v;
    __syncthreads();
    for (int d = 128; d > 0; d >>= 1) {
        if (threadIdx.x < d) s[threadIdx.x] += s[threadIdx.x + d];
        __syncthreads();
    }
    if (threadIdx.x == 0) partials[blockIdx.x] = s[0];
}

__global__ __launch_bounds__(256) void k_scan1(
    int* __restrict__ partials, int nb)
{
    __shared__ int s[256];
    int tid = threadIdx.x;
    int v = (tid < nb) ? partials[tid] : 0;
    s[tid] = v;
    __syncthreads();
    for (int d = 1; d < 256; d <<= 1) {
        int t = (tid >= d) ? s[tid - d] : 0;
        __syncthreads();
        s[tid] += t;
        __syncthreads();
    }
    if (tid < nb) partials[tid] = s[tid] - v;   // exclusive
}

__global__ __launch_bounds__(256) void k_final(
    const int* __restrict__ counts, const int* __restrict__ partials,
    int* __restrict__ offsets, int* __restrict__ cursor, int n_nodes)
{
    __shared__ int s[256];
    int tid = threadIdx.x;
    int i = blockIdx.x * 256 + tid;
    int v = (i < n_nodes) ? counts[i] : 0;
    s[tid] = v;
    __syncthreads();
    for (int d = 1; d < 256; d <<= 1) {
        int t = (tid >= d) ? s[tid - d] : 0;
        __syncthreads();
        s[tid] += t;
        __syncthreads();
    }
    if (i < n_nodes) {
        int off = partials[blockIdx.x] + s[tid] - v;
        offsets[i] = off;
        cursor[i] = off;
    }
}

__global__ __launch_bounds__(256) void k_fill(
    const int* __restrict__ src, const int* __restrict__ dst,
    int* __restrict__ cursor, u16* __restrict__ elist, int n_edges)
{
    int e = blockIdx.x * 256 + threadIdx.x;
    if (e < n_edges) {
        int pos = atomicAdd(&cursor[dst[e]], 1);
        elist[pos] = (u16)src[e];
    }
}

// ---- fused: gather(all batches at once) + self + 64x64 matmul ----
// hb layout: (N, B*C) bf16. One wave per node; lane l covers batch l>>4,
// channels (l&15)*4 .. +3 (one uint2 = 8B per gather). Block = 4 waves = 4 nodes.
__global__ __launch_bounds__(256) void gin_fused3(
    const u16* __restrict__ hb,
    const u16* __restrict__ elist,
    const int* __restrict__ offsets,
    const float* __restrict__ W,      // (64,64) row-major (out,in)
    const float* __restrict__ bias,
    float* __restrict__ out_f32,      // (B,N,C) fp32, nullable
    u16* __restrict__ out_bf,         // (N,B*C) bf16, nullable
    int n_nodes, int n_edges)
{
    __shared__ float Ws[64][65];
    __shared__ float rows[2][4][4][64];   // [buf][node-slot][batch][ch]
    int tid = threadIdx.x;
    for (int i = tid; i < 64 * 64; i += 256)
        Ws[i >> 6][i & 63] = W[i];

    int w = tid >> 6;               // node slot within block
    int l = tid & 63;
    int bl = l >> 4;                // gather-phase batch
    int cq = (l & 15) << 2;         // gather-phase channel quad
    float bia = bias[l];

    const u16* px = hb + (l << 2);  // lane base (8B per node row slice)

    int p = 0;
    for (int node0 = blockIdx.x * 4; node0 < n_nodes;
         node0 += gridDim.x * 4, p ^= 1) {
        int node = node0 + w;
        float a0 = 0.f, a1 = 0.f, a2 = 0.f, a3 = 0.f;
        if (node < n_nodes) {
            int ks = offsets[node];
            int ke = (node + 1 < n_nodes) ? offsets[node + 1] : n_edges;
            uint2 sv = *(const uint2*)(px + ((size_t)node << 8));   // self
            a0 = lo16(sv.x); a1 = hi16(sv.x); a2 = lo16(sv.y); a3 = hi16(sv.y);
            int k = ks;
            for (; k + 4 <= ke; k += 4) {
                int s0 = elist[k + 0];
                int s1 = elist[k + 1];
                int s2 = elist[k + 2];
                int s3 = elist[k + 3];
                uint2 v0 = *(const uint2*)(px + ((size_t)s0 << 8));
                uint2 v1 = *(const uint2*)(px + ((size_t)s1 << 8));
                uint2 v2 = *(const uint2*)(px + ((size_t)s2 << 8));
                uint2 v3 = *(const uint2*)(px + ((size_t)s3 << 8));
                a0 += lo16(v0.x); a1 += hi16(v0.x); a2 += lo16(v0.y); a3 += hi16(v0.y);
                a0 += lo16(v1.x); a1 += hi16(v1.x); a2 += lo16(v1.y); a3 += hi16(v1.y);
                a0 += lo16(v2.x); a1 += hi16(v2.x); a2 += lo16(v2.y); a3 += hi16(v2.y);
                a0 += lo16(v3.x); a1 += hi16(v3.x); a2 += lo16(v3.y); a3 += hi16(v3.y);
            }
            for (; k < ke; ++k) {
                uint2 v = *(const uint2*)(px + ((size_t)elist[k] << 8));
                a0 += lo16(v.x); a1 += hi16(v.x); a2 += lo16(v.y); a3 += hi16(v.y);
            }
        }
        *(float4*)&rows[p][w][bl][cq] = make_float4(a0, a1, a2, a3);
        __syncthreads();
        if (node < n_nodes) {
            float o0 = bia, o1 = bia, o2 = bia, o3 = bia;
            int c = l;
#pragma unroll
            for (int k4 = 0; k4 < 64; k4 += 4) {
                float4 r0 = *(const float4*)&rows[p][w][0][k4];
                float4 r1 = *(const float4*)&rows[p][w][1][k4];
                float4 r2 = *(const float4*)&rows[p][w][2][k4];
                float4 r3 = *(const float4*)&rows[p][w][3][k4];
                float w0 = Ws[c][k4 + 0], w1 = Ws[c][k4 + 1];
                float w2 = Ws[c][k4 + 2], w3 = Ws[c][k4 + 3];
                o0 += r0.x * w0 + r0.y * w1 + r0.z * w2 + r0.w * w3;
                o1 += r1.x * w0 + r1.y * w1 + r1.z * w2 + r1.w * w3;
                o2 += r2.x * w0 + r2.y * w1 + r2.z * w2 + r2.w * w3;
                o3 += r3.x * w0 + r3.y * w1 + r3.z * w2 + r3.w * w3;
            }
            if (out_bf) {
                size_t ob = (size_t)node << 8;
                out_bf[ob + 0 * 64 + c] = f2bf(o0);
                out_bf[ob + 1 * 64 + c] = f2bf(o1);
                out_bf[ob + 2 * 64 + c] = f2bf(o2);
                out_bf[ob + 3 * 64 + c] = f2bf(o3);
            }
            if (out_f32) {
                out_f32[(((size_t)0 * n_nodes + node) << 6) + c] = o0;
                out_f32[(((size_t)1 * n_nodes + node) << 6) + c] = o1;
                out_f32[(((size_t)2 * n_nodes + node) << 6) + c] = o2;
                out_f32[(((size_t)3 * n_nodes + node) << 6) + c] = o3;
            }
        }
    }
}

// ---------------- fallback (atomic path, proven) ----------------

__global__ __launch_bounds__(256) void gin_scatter(
    const float* __restrict__ h, const int* __restrict__ src,
    const int* __restrict__ dst, float* __restrict__ agg,
    int n_edges, int n_nodes)
{
    long long i = (long long)blockIdx.x * blockDim.x + threadIdx.x;
    int e = (int)(i >> 6);
    if (e >= n_edges) return;
    int lane = (int)(i & 63);
    int b  = lane >> 4;
    int c4 = (lane & 15) << 2;
    int s = src[e];
    int d = dst[e];
    const float4 v = *reinterpret_cast<const float4*>(
        h + ((size_t)b * n_nodes + s) * C_DIM + c4);
    float* o = agg + ((size_t)b * n_nodes + d) * C_DIM + c4;
    unsafeAtomicAdd(o + 0, v.x);
    unsafeAtomicAdd(o + 1, v.y);
    unsafeAtomicAdd(o + 2, v.z);
    unsafeAtomicAdd(o + 3, v.w);
}

__global__ __launch_bounds__(256) void gin_mm(
    const float* __restrict__ hin, const float* __restrict__ agg,
    const float* __restrict__ W, const float* __restrict__ bias,
    float* __restrict__ out, int M)
{
    __shared__ float Ws[64][65];
    __shared__ float rows[4][64];
    int tid = threadIdx.x;
    for (int i = tid; i < 64 * 64; i += 256)
        Ws[i >> 6][i & 63] = W[i];
    int rloc = tid >> 6;
    int j    = tid & 63;
    int row  = blockIdx.x * 4 + rloc;
    if (row < M)
        rows[rloc][j] = hin[(size_t)row * C_DIM + j] + agg[(size_t)row * C_DIM + j];
    __syncthreads();
    if (row < M) {
        float acc = bias[j];
#pragma unroll
        for (int k = 0; k < 64; ++k)
            acc += rows[rloc][k] * Ws[j][k];
        out[(size_t)row * C_DIM + j] = acc;
    }
}

// ---------------- launch ----------------

static inline size_t align256(size_t x) { return (x + 255) & ~(size_t)255; }

extern "C" void kernel_launch(void* const* d_in, const int* in_sizes, int n_in,
                              void* d_out, int out_size, void* d_ws, size_t ws_size,
                              hipStream_t stream)
{
    const float* x   = (const float*)d_in[0];
    const int*   ei  = (const int*)d_in[1];
    const float* W1  = (const float*)d_in[2];
    const float* b1  = (const float*)d_in[3];
    const float* W2  = (const float*)d_in[4];
    const float* b2  = (const float*)d_in[5];
    float* out = (float*)d_out;

    const int n_nodes = in_sizes[0] / (B_DIM * C_DIM);
    const int n_edges = in_sizes[1] / 2;
    const int M = B_DIM * n_nodes;
    const size_t elems = (size_t)M * C_DIM;

    const int* src = ei;
    const int* dst = ei + n_edges;
    const int NB = (n_nodes + 255) / 256;

    // ws layout (fast path)
    size_t off = 0;
    size_t o_xb      = off; off = align256(off + elems * sizeof(u16));
    size_t o_h1b     = off; off = align256(off + elems * sizeof(u16));
    size_t o_counts  = off; off = align256(off + (size_t)n_nodes * sizeof(int));
    size_t o_offsets = off; off = align256(off + (size_t)n_nodes * sizeof(int));
    size_t o_cursor  = off; off = align256(off + (size_t)n_nodes * sizeof(int));
    size_t o_part    = off; off = align256(off + 256 * sizeof(int));
    size_t o_elist   = off; off = align256(off + (size_t)n_edges * sizeof(u16));
    const size_t need = off;

    const bool fast = (ws_size >= need) && (n_nodes <= 65535) && (NB <= 256) &&
                      ((elems & 7) == 0);

    dim3 blk(256);

    if (fast) {
        char* ws = (char*)d_ws;
        u16* xb      = (u16*)(ws + o_xb);
        u16* h1b     = (u16*)(ws + o_h1b);
        int* counts  = (int*)(ws + o_counts);
        int* offsets = (int*)(ws + o_offsets);
        int* cursor  = (int*)(ws + o_cursor);
        int* partials= (int*)(ws + o_part);
        u16* elist   = (u16*)(ws + o_elist);

        dim3 grid_cv((n_nodes * 32 + 255) / 256);
        dim3 grid_e((n_edges + 255) / 256);
        dim3 grid_n((unsigned)NB);
        dim3 grid_f(2048);

        hipMemsetAsync(counts, 0, (size_t)n_nodes * sizeof(int), stream);
        k_f2bf_t<<<grid_cv, blk, 0, stream>>>(x, xb, n_nodes);
        k_hist<<<grid_e, blk, 0, stream>>>(dst, counts, n_edges);
        k_part<<<grid_n, blk, 0, stream>>>(counts, partials, n_nodes);
        k_scan1<<<1, blk, 0, stream>>>(partials, NB);
        k_final<<<grid_n, blk, 0, stream>>>(counts, partials, offsets, cursor, n_nodes);
        k_fill<<<grid_e, blk, 0, stream>>>(src, dst, cursor, elist, n_edges);

        // layer 1: bf16 (N,BC) -> bf16 (N,BC)
        gin_fused3<<<grid_f, blk, 0, stream>>>(xb, elist, offsets, W1, b1,
                                               nullptr, h1b, n_nodes, n_edges);
        // layer 2: bf16 (N,BC) -> fp32 (B,N,C)
        gin_fused3<<<grid_f, blk, 0, stream>>>(h1b, elist, offsets, W2, b2,
                                               out, nullptr, n_nodes, n_edges);
    } else {
        // fallback: atomic path
        float* agg = (float*)d_ws;
        const size_t h_bytes = elems * sizeof(float);
        dim3 grid_sc((unsigned)(((long long)n_edges * 64 + 255) / 256));
        dim3 grid_mm((unsigned)((M + 3) / 4));

        hipMemsetAsync(agg, 0, h_bytes, stream);
        gin_scatter<<<grid_sc, blk, 0, stream>>>(x, src, dst, agg, n_edges, n_nodes);
        gin_mm<<<grid_mm, blk, 0, stream>>>(x, agg, W1, b1, out, M);

        hipMemsetAsync(agg, 0, h_bytes, stream);
        gin_scatter<<<grid_sc, blk, 0, stream>>>(out, src, dst, agg, n_edges, n_nodes);
        gin_mm<<<grid_mm, blk, 0, stream>>>(out, agg, W2, b2, out, M);
    }
}